// Round 3
// baseline (755.218 us; speedup 1.0000x reference)
//
#include <hip/hip_runtime.h>

#define H 512
#define W 512
#define HW (H * W)
#define T 128
#define DECAY 0.8f

#define RS 42      // LDS row stride (words), region 40x40
#define RGY 40
#define NCH 400    // float4 chunks per region (40 rows x 10)

__device__ __forceinline__ float4 zero4() { return make_float4(0.f, 0.f, 0.f, 0.f); }

// ---------------------------------------------------------------------------
// Prepass A: pointwise double-EMA scan of x[0..63] -> p64, r64 planes.
// ---------------------------------------------------------------------------
__global__ __launch_bounds__(256) void scan64(
    const float* __restrict__ x, float* __restrict__ pout, float* __restrict__ rout)
{
    int px = blockIdx.x * 256 + threadIdx.x;
    float p = 0.f, r = 0.f;
    const float* xp = x + px;
    #pragma unroll 8
    for (int t = 0; t < 64; ++t) {
        float xv = xp[(size_t)t * HW];
        float rn = __builtin_fmaf(DECAY, r, p);   // r' = .8r + p_old
        p = __builtin_fmaf(DECAY, p, xv);         // p' = .8p + x
        r = rn;
    }
    pout[px] = p;
    rout[px] = r;
}

// ---------------------------------------------------------------------------
// Shared conv machinery (tile 32x32, 256 threads, 2x2 patch per thread).
// ---------------------------------------------------------------------------
#define CONV_SETUP()                                                          \
    const int tid = threadIdx.x;                                              \
    const int tX = blockIdx.x, tY = blockIdx.y;                               \
    const int X0 = tX * 32 - 4, Y0 = tY * 32 - 4;                             \
    int c1 = tid + 256;                                                       \
    int r0 = tid / 10, q0 = tid - r0 * 10;                                    \
    int r1 = c1 / 10, q1 = c1 - r1 * 10;                                      \
    int gy0 = Y0 + r0, gx0 = X0 + q0 * 4;                                     \
    int gy1 = Y0 + r1, gx1 = X0 + q1 * 4;                                     \
    bool v0 = (unsigned)gy0 < H && (unsigned)gx0 < W;                         \
    bool w1 = (c1 < NCH);                                                     \
    bool v1 = w1 && (unsigned)gy1 < H && (unsigned)gx1 < W;                   \
    size_t go0 = v0 ? ((size_t)gy0 * W + gx0) : 0;                            \
    size_t go1 = v1 ? ((size_t)gy1 * W + gx1) : 0;                            \
    int la0 = r0 * RS + q0 * 4, la1 = r1 * RS + q1 * 4;                       \
    const int cx = tid & 15, cyp = tid >> 4;                                  \
    const int wb = (2 * cyp) * RS + 2 * cx;                                   \
    const int orow = tY * 32 + 2 * cyp, ocol = tX * 32 + 2 * cx;

#define CONV_BODY(bufR, y00, y01, y10, y11)                                   \
    _Pragma("unroll")                                                         \
    for (int ir = 0; ir < 10; ++ir) {                                         \
        float win[10];                                                        \
        const float* rp = bufR + wb + ir * RS;                                \
        _Pragma("unroll")                                                     \
        for (int j = 0; j < 5; ++j) {                                         \
            float2 v = *(const float2*)(rp + 2 * j);                          \
            win[2 * j] = v.x; win[2 * j + 1] = v.y;                           \
        }                                                                     \
        if (ir < 9) {                                                         \
            _Pragma("unroll")                                                 \
            for (int kx = 0; kx < 9; ++kx) {                                  \
                float wv = wr[ir * 9 + kx];                                   \
                y00 = __builtin_fmaf(wv, win[kx], y00);                       \
                y01 = __builtin_fmaf(wv, win[kx + 1], y01);                   \
            }                                                                 \
        }                                                                     \
        if (ir > 0) {                                                         \
            _Pragma("unroll")                                                 \
            for (int kx = 0; kx < 9; ++kx) {                                  \
                float wv = wr[(ir - 1) * 9 + kx];                             \
                y10 = __builtin_fmaf(wv, win[kx], y10);                       \
                y11 = __builtin_fmaf(wv, win[kx + 1], y11);                   \
            }                                                                 \
        }                                                                     \
    }

// ---------------------------------------------------------------------------
// Prepass B: conv9x9 of one plane (zero pad). grid.z selects plane 0/1:
//   in = ws + z*HW (p64/r64), out = ws + (2+z)*HW (P64/S64).
// ---------------------------------------------------------------------------
__global__ __launch_bounds__(256, 2) void conv_plane(
    const float* __restrict__ ws_base, const float* __restrict__ wp)
{
    __shared__ float xb[RGY * RS];
    const float* in = ws_base + (size_t)blockIdx.z * HW;
    float* outp = (float*)(ws_base + (size_t)(2 + blockIdx.z) * HW);

    CONV_SETUP();

    float wr[81];
    #pragma unroll
    for (int i = 0; i < 81; ++i) wr[i] = wp[i];

    float4 a = v0 ? *(const float4*)(in + go0) : zero4();
    float4 b = v1 ? *(const float4*)(in + go1) : zero4();
    *(float4*)(xb + la0) = a;
    if (w1) *(float4*)(xb + la1) = b;
    __syncthreads();

    float y00 = 0.f, y01 = 0.f, y10 = 0.f, y11 = 0.f;
    CONV_BODY(xb, y00, y01, y10, y11);

    *(float2*)(outp + (size_t)orow * W + ocol) = make_float2(y00, y01);
    *(float2*)(outp + (size_t)(orow + 1) * W + ocol) = make_float2(y10, y11);
}

// ---------------------------------------------------------------------------
// Main fused kernel: per block = one 32x32 tile for 64 timesteps (phase z).
//   out[t] = S;  S = .8S + P;  P = .8P + conv(x[t]).
// x-tile double-buffered in LDS, 2-step register prefetch, 1 barrier/step.
// ---------------------------------------------------------------------------
__global__ __launch_bounds__(256, 2) void snn_main(
    const float* __restrict__ x, const float* __restrict__ wp,
    const float* __restrict__ ws_base, float* __restrict__ out)
{
    __shared__ float xb0[RGY * RS];
    __shared__ float xb1[RGY * RS];

    const int ph = blockIdx.z;
    const int tb = ph * 64;

    CONV_SETUP();

    float wr[81];
    #pragma unroll
    for (int i = 0; i < 81; ++i) wr[i] = wp[i];

    float* op0 = out + (size_t)tb * HW + (size_t)orow * W + ocol;

    float P00, P01, P10, P11, S00, S01, S10, S11;
    if (ph == 0) {
        P00 = P01 = P10 = P11 = 0.f;
        S00 = S01 = S10 = S11 = 0.f;
    } else {
        const float* Pin = ws_base + 2 * (size_t)HW;
        const float* Sin = ws_base + 3 * (size_t)HW;
        size_t o = (size_t)orow * W + ocol;
        float2 a = *(const float2*)(Pin + o);     P00 = a.x; P01 = a.y;
        float2 b = *(const float2*)(Pin + o + W); P10 = b.x; P11 = b.y;
        float2 c = *(const float2*)(Sin + o);     S00 = c.x; S01 = c.y;
        float2 d = *(const float2*)(Sin + o + W); S10 = d.x; S11 = d.y;
    }

#define LOADR(RA_, RB_, tplane)                                               \
    {                                                                         \
        int _t = (tplane); if (_t > T - 1) _t = T - 1;                        \
        const float* _xp = x + (size_t)_t * HW;                               \
        RA_ = v0 ? *(const float4*)(_xp + go0) : zero4();                     \
        RB_ = v1 ? *(const float4*)(_xp + go1) : zero4();                     \
    }

#define STG(buf, RA_, RB_)                                                    \
    {                                                                         \
        *(float4*)(buf + la0) = RA_;                                          \
        if (w1) *(float4*)(buf + la1) = RB_;                                  \
    }

#define STEP(bufR, bufW, WR0, WR1, tnext)                                     \
    {                                                                         \
        *(float2*)op0 = make_float2(S00, S01);                                \
        *(float2*)(op0 + W) = make_float2(S10, S11);                          \
        op0 += HW;                                                            \
        float y00 = 0.f, y01 = 0.f, y10 = 0.f, y11 = 0.f;                     \
        CONV_BODY(bufR, y00, y01, y10, y11);                                  \
        S00 = __builtin_fmaf(DECAY, S00, P00);                                \
        P00 = __builtin_fmaf(DECAY, P00, y00);                                \
        S01 = __builtin_fmaf(DECAY, S01, P01);                                \
        P01 = __builtin_fmaf(DECAY, P01, y01);                                \
        S10 = __builtin_fmaf(DECAY, S10, P10);                                \
        P10 = __builtin_fmaf(DECAY, P10, y10);                                \
        S11 = __builtin_fmaf(DECAY, S11, P11);                                \
        P11 = __builtin_fmaf(DECAY, P11, y11);                                \
        STG(bufW, WR0, WR1);                                                  \
        LOADR(WR0, WR1, tnext);                                               \
        __syncthreads();                                                      \
    }

    float4 RA0, RA1, RB0, RB1;
    LOADR(RA0, RA1, tb);        // x[tb]
    LOADR(RB0, RB1, tb + 1);    // x[tb+1]
    STG(xb0, RA0, RA1);
    LOADR(RA0, RA1, tb + 2);    // x[tb+2]
    __syncthreads();

    for (int s = 0; s < 64; s += 2) {
        STEP(xb0, xb1, RB0, RB1, tb + s + 3);  // conv x[tb+s];   stage x[tb+s+1]
        STEP(xb1, xb0, RA0, RA1, tb + s + 4);  // conv x[tb+s+1]; stage x[tb+s+2]
    }
#undef STEP
#undef STG
#undef LOADR
}

// ---------------------------------------------------------------------------
extern "C" void kernel_launch(void* const* d_in, const int* in_sizes, int n_in,
                              void* d_out, int out_size, void* d_ws, size_t ws_size,
                              hipStream_t stream) {
    const float* x = (const float*)d_in[0];  // [128,1,512,512]
    const float* w = (const float*)d_in[1];  // [1,1,9,9]
    float* out = (float*)d_out;              // [128,1,512,512]
    float* ws = (float*)d_ws;                // 4 planes: p64, r64, P64, S64

    scan64<<<dim3(HW / 256), 256, 0, stream>>>(x, ws, ws + HW);
    conv_plane<<<dim3(16, 16, 2), 256, 0, stream>>>(ws, w);
    snn_main<<<dim3(16, 16, 2), 256, 0, stream>>>(x, w, ws, out);
}

// Round 4
// 137.372 us; speedup vs baseline: 5.4976x; 5.4976x over previous
//
#include <hip/hip_runtime.h>

#define H 512
#define W 512
#define HW (H * W)
#define T 128
#define DECAY 0.8f

// ---------------------------------------------------------------------------
// Pass A: pointwise double-EMA scan, float2 lanes, pure stream.
//   p' = .8p + x[t];  r' = .8r + p_old;  Rbuf[t] = r entering step t.
// ---------------------------------------------------------------------------
__global__ __launch_bounds__(256) void scan_chunk(
    const float* __restrict__ x, float* __restrict__ Rbuf,
    float* __restrict__ state, int t0, int tc)
{
    int gid = blockIdx.x * 256 + threadIdx.x;        // 0 .. HW/2-1
    const float2* xp = (const float2*)x + (size_t)t0 * (HW / 2) + gid;
    float2* rp = (float2*)Rbuf + gid;
    float2* st = (float2*)state;

    float2 p, r;
    if (t0 == 0) {
        p = make_float2(0.f, 0.f);
        r = make_float2(0.f, 0.f);
    } else {
        p = st[gid];
        r = st[HW / 2 + gid];
    }
    #pragma unroll 4
    for (int t = 0; t < tc; ++t) {
        rp[(size_t)t * (HW / 2)] = r;
        float2 xv = xp[(size_t)t * (HW / 2)];
        float2 rn;
        rn.x = __builtin_fmaf(DECAY, r.x, p.x);
        rn.y = __builtin_fmaf(DECAY, r.y, p.y);
        p.x = __builtin_fmaf(DECAY, p.x, xv.x);
        p.y = __builtin_fmaf(DECAY, p.y, xv.y);
        r = rn;
    }
    st[gid] = p;
    st[HW / 2 + gid] = r;
}

// ---------------------------------------------------------------------------
// Pass B: 9x9 conv, zero pad 4. Tile 64 wide x 128 tall per block, one plane
// per blockIdx.z. Register-rotating rows: each thread owns a 4w x 8t patch,
// reads each of its 16 input rows ONCE (3x b128) and feeds all pending
// output rows -> 24 B LDS per output px. Stride 76 words: b128 reads from 16
// x-lanes spread uniformly over all 32 banks (8 words/bank = b128 minimum).
// ---------------------------------------------------------------------------
#define BX 64
#define BY 128
#define RW 72       // region width  (64 + 8)
#define RH 136      // region height (128 + 8)
#define RSTR 76     // LDS row stride in words
#define RCH 18      // float4 chunks per region row

__global__ __launch_bounds__(256) void conv_chunk(
    const float* __restrict__ Rbuf, const float* __restrict__ wp,
    float* __restrict__ out, int t0)
{
    __shared__ float reg[RH * RSTR];   // 41,344 B

    const int tid = threadIdx.x;
    const int tX = blockIdx.x, tY = blockIdx.y, tz = blockIdx.z;
    const int X0 = tX * BX - 4, Y0 = tY * BY - 4;
    const float* Rp = Rbuf + (size_t)tz * HW;

    float wr[81];
    #pragma unroll
    for (int q = 0; q < 81; ++q) wr[q] = wp[q];

    // stage region (all chunks 16B-aligned in global; pad -> zeros)
    for (int e = tid; e < RH * RCH; e += 256) {
        int rr = e / RCH, c = e - rr * RCH;
        int gy = Y0 + rr, gx = X0 + 4 * c;
        float4 v = make_float4(0.f, 0.f, 0.f, 0.f);
        if ((unsigned)gy < H && (unsigned)gx < W)
            v = *(const float4*)(Rp + (size_t)gy * W + gx);
        *(float4*)(&reg[rr * RSTR + 4 * c]) = v;
    }
    __syncthreads();

    const int i = tid & 15;     // x patch: cols 4i..4i+3 (tile-local)
    const int j = tid >> 4;     // y patch: rows 8j..8j+7
    const int lx = 4 * i;       // window col base in region (= out col - 4 + 4)
    const int rbase = 8 * j;    // first window row in region

    float acc[8][4];
    #pragma unroll
    for (int a = 0; a < 8; ++a)
        #pragma unroll
        for (int b = 0; b < 4; ++b) acc[a][b] = 0.f;

    #pragma unroll
    for (int r = 0; r < 16; ++r) {
        float win[12];
        const float* rp = &reg[(rbase + r) * RSTR + lx];
        #pragma unroll
        for (int q = 0; q < 3; ++q) {
            float4 v = *(const float4*)(rp + 4 * q);
            win[4 * q + 0] = v.x; win[4 * q + 1] = v.y;
            win[4 * q + 2] = v.z; win[4 * q + 3] = v.w;
        }
        #pragma unroll
        for (int oy = 0; oy < 8; ++oy) {
            const int ky = r - oy;                 // compile-time after unroll
            if (ky >= 0 && ky <= 8) {
                #pragma unroll
                for (int kx = 0; kx < 9; ++kx) {
                    float wv = wr[ky * 9 + kx];
                    acc[oy][0] = __builtin_fmaf(wv, win[kx + 0], acc[oy][0]);
                    acc[oy][1] = __builtin_fmaf(wv, win[kx + 1], acc[oy][1]);
                    acc[oy][2] = __builtin_fmaf(wv, win[kx + 2], acc[oy][2]);
                    acc[oy][3] = __builtin_fmaf(wv, win[kx + 3], acc[oy][3]);
                }
            }
        }
    }

    float* op = out + (size_t)(t0 + tz) * HW
                    + (size_t)(tY * BY + 8 * j) * W + (tX * BX + 4 * i);
    #pragma unroll
    for (int oy = 0; oy < 8; ++oy)
        *(float4*)(op + (size_t)oy * W) =
            make_float4(acc[oy][0], acc[oy][1], acc[oy][2], acc[oy][3]);
}

// ---------------------------------------------------------------------------
extern "C" void kernel_launch(void* const* d_in, const int* in_sizes, int n_in,
                              void* d_out, int out_size, void* d_ws, size_t ws_size,
                              hipStream_t stream) {
    const float* x = (const float*)d_in[0];  // [128,1,512,512]
    const float* w = (const float*)d_in[1];  // [1,1,9,9]
    float* out = (float*)d_out;              // [128,1,512,512]

    float* state = (float*)d_ws;             // 2 planes: p, r carry
    float* Rbuf = state + 2 * (size_t)HW;

    size_t plane = (size_t)HW * sizeof(float);
    int maxTc = 1;
    if (ws_size > 3 * plane)
        maxTc = (int)((ws_size - 2 * plane) / plane);
    int Tc = T;
    if (Tc > maxTc) Tc = maxTc;
    if (Tc < 1) Tc = 1;

    for (int t0 = 0; t0 < T; t0 += Tc) {
        int tc = T - t0;
        if (tc > Tc) tc = Tc;
        scan_chunk<<<dim3(HW / 512), 256, 0, stream>>>(x, Rbuf, state, t0, tc);
        conv_chunk<<<dim3(W / BX, H / BY, tc), 256, 0, stream>>>(Rbuf, w, out, t0);
    }
}

// Round 5
// 135.363 us; speedup vs baseline: 5.5792x; 1.0148x over previous
//
#include <hip/hip_runtime.h>

#define H 512
#define W 512
#define HW (H * W)
#define T 128
#define DECAY 0.8f

__device__ __forceinline__ unsigned short f2bf_rne(float f) {
    unsigned int u = __float_as_uint(f);
    unsigned int r = (u + 0x7fffu + ((u >> 16) & 1u)) >> 16;
    return (unsigned short)r;
}
__device__ __forceinline__ float bf_lo(unsigned int u) {
    return __uint_as_float(u << 16);
}
__device__ __forceinline__ float bf_hi(unsigned int u) {
    return __uint_as_float(u & 0xffff0000u);
}

// ---------------------------------------------------------------------------
// Pass A: pointwise double-EMA scan, float2 lanes; R stored as packed bf16.
//   p' = .8p + x[t];  r' = .8r + p_old;  Rbuf[t] = r entering step t.
// ---------------------------------------------------------------------------
__global__ __launch_bounds__(256) void scan_chunk(
    const float* __restrict__ x, unsigned int* __restrict__ Rbuf,
    float* __restrict__ state, int t0, int tc)
{
    int gid = blockIdx.x * 256 + threadIdx.x;        // 0 .. HW/2-1
    const float2* xp = (const float2*)x + (size_t)t0 * (HW / 2) + gid;
    unsigned int* rp = Rbuf + gid;                   // 2 bf16 per lane
    float2* st = (float2*)state;

    float2 p, r;
    if (t0 == 0) {
        p = make_float2(0.f, 0.f);
        r = make_float2(0.f, 0.f);
    } else {
        p = st[gid];
        r = st[HW / 2 + gid];
    }
    #pragma unroll 4
    for (int t = 0; t < tc; ++t) {
        rp[(size_t)t * (HW / 2)] =
            (unsigned int)f2bf_rne(r.x) | ((unsigned int)f2bf_rne(r.y) << 16);
        float2 xv = xp[(size_t)t * (HW / 2)];
        float2 rn;
        rn.x = __builtin_fmaf(DECAY, r.x, p.x);
        rn.y = __builtin_fmaf(DECAY, r.y, p.y);
        p.x = __builtin_fmaf(DECAY, p.x, xv.x);
        p.y = __builtin_fmaf(DECAY, p.y, xv.y);
        r = rn;
    }
    st[gid] = p;
    st[HW / 2 + gid] = r;
}

// ---------------------------------------------------------------------------
// Pass B: 9x9 conv, zero pad 4, bf16 input / fp32 output.
// Tile 256 wide x 32 tall. Thread: i = tid&63 -> 4-wide col run, j = tid>>6 ->
// 8-tall patch. A wave (64 lanes) = ONE region row: every ds_read/ds_write is
// 64 lanes x contiguous bytes -> structurally conflict-free. Register-rotating
// rows: each thread reads its 16 input rows once, feeding 8 pending outputs.
// ---------------------------------------------------------------------------
#define BX 256
#define BY 32
#define RGROWS 40     // 32 + 8 halo
#define RELEMS 264    // 256 + 8 halo (bf16 elems)
#define RSTRE 272     // LDS row stride in bf16 elems (544 B)
#define RCHUNK 66     // 4-elem (8 B) chunks per row

__global__ __launch_bounds__(256) void conv_chunk(
    const unsigned short* __restrict__ Rbuf, const float* __restrict__ wp,
    float* __restrict__ out, int t0)
{
    __shared__ unsigned short reg[RGROWS * RSTRE];   // 21,760 B

    const int tid = threadIdx.x;
    const int tX = blockIdx.x, tY = blockIdx.y, tz = blockIdx.z;
    const int X0 = tX * BX - 4, Y0 = tY * BY - 4;
    const unsigned short* Rp = Rbuf + (size_t)tz * HW;

    float wr[81];
    #pragma unroll
    for (int q = 0; q < 81; ++q) wr[q] = wp[q];

    // stage region (bf16, 8B chunks; chunks never straddle the image edge)
    for (int e = tid; e < RGROWS * RCHUNK; e += 256) {
        int rr = e / RCHUNK, c = e - rr * RCHUNK;
        int gy = Y0 + rr, gx = X0 + 4 * c;
        uint2 v = make_uint2(0u, 0u);
        if ((unsigned)gy < H && (unsigned)gx < W)
            v = *(const uint2*)(Rp + (size_t)gy * W + gx);
        *(uint2*)(&reg[rr * RSTRE + 4 * c]) = v;
    }
    __syncthreads();

    const int i = tid & 63;     // col chunk: elems 4i..4i+11 window
    const int j = tid >> 6;     // 0..3 -> rows 8j..8j+7
    const int rbase = 8 * j;

    float acc[8][4];
    #pragma unroll
    for (int a = 0; a < 8; ++a)
        #pragma unroll
        for (int b = 0; b < 4; ++b) acc[a][b] = 0.f;

    #pragma unroll
    for (int r = 0; r < 16; ++r) {
        const unsigned short* rp = &reg[(rbase + r) * RSTRE + 4 * i];
        uint2 va = *(const uint2*)(rp);      // elems 0..3
        uint2 vb = *(const uint2*)(rp + 4);  // elems 4..7
        uint2 vc = *(const uint2*)(rp + 8);  // elems 8..11
        float win[12];
        win[0] = bf_lo(va.x);  win[1] = bf_hi(va.x);
        win[2] = bf_lo(va.y);  win[3] = bf_hi(va.y);
        win[4] = bf_lo(vb.x);  win[5] = bf_hi(vb.x);
        win[6] = bf_lo(vb.y);  win[7] = bf_hi(vb.y);
        win[8] = bf_lo(vc.x);  win[9] = bf_hi(vc.x);
        win[10] = bf_lo(vc.y); win[11] = bf_hi(vc.y);
        #pragma unroll
        for (int oy = 0; oy < 8; ++oy) {
            const int ky = r - oy;                 // compile-time after unroll
            if (ky >= 0 && ky <= 8) {
                #pragma unroll
                for (int kx = 0; kx < 9; ++kx) {
                    float wv = wr[ky * 9 + kx];
                    acc[oy][0] = __builtin_fmaf(wv, win[kx + 0], acc[oy][0]);
                    acc[oy][1] = __builtin_fmaf(wv, win[kx + 1], acc[oy][1]);
                    acc[oy][2] = __builtin_fmaf(wv, win[kx + 2], acc[oy][2]);
                    acc[oy][3] = __builtin_fmaf(wv, win[kx + 3], acc[oy][3]);
                }
            }
        }
    }

    float* op = out + (size_t)(t0 + tz) * HW
                    + (size_t)(tY * BY + 8 * j) * W + (tX * BX + 4 * i);
    #pragma unroll
    for (int oy = 0; oy < 8; ++oy)
        *(float4*)(op + (size_t)oy * W) =
            make_float4(acc[oy][0], acc[oy][1], acc[oy][2], acc[oy][3]);
}

// ---------------------------------------------------------------------------
extern "C" void kernel_launch(void* const* d_in, const int* in_sizes, int n_in,
                              void* d_out, int out_size, void* d_ws, size_t ws_size,
                              hipStream_t stream) {
    const float* x = (const float*)d_in[0];  // [128,1,512,512]
    const float* w = (const float*)d_in[1];  // [1,1,9,9]
    float* out = (float*)d_out;              // [128,1,512,512]

    float* state = (float*)d_ws;                               // 2 fp32 planes
    unsigned short* Rbuf = (unsigned short*)(state + 2 * (size_t)HW);

    size_t state_b = 2 * (size_t)HW * sizeof(float);
    size_t plane_b = (size_t)HW * sizeof(unsigned short);
    int maxTc = 1;
    if (ws_size > state_b + plane_b)
        maxTc = (int)((ws_size - state_b) / plane_b);
    int Tc = T;
    if (Tc > maxTc) Tc = maxTc;
    if (Tc < 1) Tc = 1;

    for (int t0 = 0; t0 < T; t0 += Tc) {
        int tc = T - t0;
        if (tc > Tc) tc = Tc;
        scan_chunk<<<dim3(HW / 512), 256, 0, stream>>>(
            x, (unsigned int*)Rbuf, state, t0, tc);
        conv_chunk<<<dim3(W / BX, H / BY, tc), 256, 0, stream>>>(
            Rbuf, w, out, t0);
    }
}